// Round 7
// baseline (6347.733 us; speedup 1.0000x reference)
//
#include <hip/hip_runtime.h>

#define T_STEPS 25
#define BATCH   128
#define D_IN    2048
#define H_DIM   4096
#define C_DIM   1000
#define N_ALL   3200
#define GEMM_Q  320   // OpenBLAS SGEMM_DEFAULT_Q, SKYLAKEX path (verified bit-exact R7-R16)
#define P_K2048 7     // panels: 320x5, 224, 224
#define P_K4096 13    // panels: 320x11, 288, 288
#define WOT_LD  1024  // wo^T padded out-M (1000 -> 1024, pad rows zero)

typedef __attribute__((address_space(1))) const void gas_t;
typedef __attribute__((address_space(3))) void las_t;

// OpenBLAS level3 K-panel schedule (verified bit-exact R7):
__device__ __forceinline__ int panel_len(int rem) {
    return (rem >= 2 * GEMM_Q) ? GEMM_Q
         : (rem > GEMM_Q ? ((rem / 2 + 15) & ~15) : rem);
}

// ---------------- transpose (+optional mask premultiply, zero-pad): dst[K][MT] ----------------
// Mask entries are exactly 0/1, so w*m is the identical fp32 product the reference forms.
__global__ __launch_bounds__(256)
void tmask_k(float* __restrict__ dst, const float* __restrict__ src,
             const float* __restrict__ msk, int M, int K, int MT)
{
    __shared__ float t[32][33];
    const int tx = threadIdx.x, ty = threadIdx.y;
    const int k0 = blockIdx.x * 32, m0 = blockIdx.y * 32;
    #pragma unroll
    for (int i = 0; i < 4; ++i) {
        const int m = m0 + ty + 8 * i;
        float v = 0.f;
        if (m < M) {
            const size_t gi = (size_t)m * K + k0 + tx;
            v = src[gi];
            if (msk) v *= msk[gi];
        }
        t[ty + 8 * i][tx] = v;
    }
    __syncthreads();
    const int mc = m0 + tx;
    if (mc < MT) {
        #pragma unroll
        for (int i = 0; i < 4; ++i)
            dst[(size_t)(k0 + ty + 8 * i) * MT + mc] = t[tx][ty + 8 * i];
    }
}

// ---------------- 2-wave shared-B GEMM: block = 64m x 128b, wave = 32m x 128b, lane = 8m x 8b ----------------
// R6 structure (verified exact, 73.4us) with a rebalanced lane tile: RM=8 m-rows x C=8
// cols per lane (was 8x4). R6 PMC showed round ~8800cyc = VALU 3328 (42% busy) + LDS
// 4992 (57%) with ~zero overlap (per-tile barrier convoy). LDS insts scale (RM+C)/4
// per k, fmaf RM*C: at 8x8 the per-CU-round LDS drops to 3328 = VALU -> serial-sum
// ceiling 6656 vs 8328. VMEM stays 12 insts/block-tile (B 8KB staged once per block:
// 8 global_load_lds; A 2/wave). All values pass through LDS bit-unmodified; each
// output's ascending-k fmaf chain + OpenBLAS panel split untouched -> bit-exact.
// Cadence per tile (R6-proven): [stage ti+1 -> buf^1 (6 insts/wave)] [compute ti]
// [__syncthreads]. part[p][m][b] = ascending-k fmaf chain per panel from zero;
// cross-panel folds ascend in the reduce kernels.
#define FMA8(AS, R)                                                   \
    acc[R][0].x = fmaf(AS, bv0.x, acc[R][0].x);                       \
    acc[R][0].y = fmaf(AS, bv0.y, acc[R][0].y);                       \
    acc[R][0].z = fmaf(AS, bv0.z, acc[R][0].z);                       \
    acc[R][0].w = fmaf(AS, bv0.w, acc[R][0].w);                       \
    acc[R][1].x = fmaf(AS, bv1.x, acc[R][1].x);                       \
    acc[R][1].y = fmaf(AS, bv1.y, acc[R][1].y);                       \
    acc[R][1].z = fmaf(AS, bv1.z, acc[R][1].z);                       \
    acc[R][1].w = fmaf(AS, bv1.w, acc[R][1].w);

__global__ __launch_bounds__(128)
void gemm_w(const float* __restrict__ AT, const float* __restrict__ B,
            float* __restrict__ part, int MT, int K, int ldb, int n0)
{
#pragma clang fp reassociate(off)
    __shared__ __align__(16) float Bs[2][16][128];    // 16 KB block-shared B tile (dbuf)
    __shared__ __align__(16) float As[2][2][16][32];  // 8 KB wave-private A tiles (dbuf)
    const int tid  = threadIdx.x;
    const int w    = tid >> 6;                        // wave 0..1
    const int lane = tid & 63;
    const int mq   = lane >> 4;                       // 0..3: 8 m-rows each
    const int cg   = lane & 15;                       // col-group: 8 cols
    const int m0   = blockIdx.y * 64 + w * 32;        // wave's 32-row m tile
    const int p    = blockIdx.x;

    int pstart = 0, rem = K, pl = panel_len(K);
    for (int i = 0; i < p; ++i) { pstart += pl; rem -= pl; pl = panel_len(rem); }
    const int nt = pl >> 4;                           // 320/288/224 all /16

    float4 acc[8][2];
    #pragma unroll
    for (int r = 0; r < 8; ++r) {
        acc[r][0] = make_float4(0.f, 0.f, 0.f, 0.f);
        acc[r][1] = make_float4(0.f, 0.f, 0.f, 0.f);
    }

    // A stage (per wave): [16k][32m] tile = 2KB = 2 insts; lane l -> (row l>>3, col (l&7)*4)
    const int akr = lane >> 3, amq = (lane & 7) * 4;
    const float* ap = AT + (size_t)(pstart + akr) * MT + m0 + amq;
    // B stage (2-wave cooperative): wave w rows w*8..w*8+7 via 4 insts;
    // inst i: lanes 0-31 -> row w*8+2i col (lane&31)*4, lanes 32-63 -> row w*8+2i+1
    const float* bsrc = B + (size_t)(pstart + w * 8 + (lane >> 5)) * ldb + n0 + (lane & 31) * 4;

    {   // prologue: stage tile 0
        __builtin_amdgcn_global_load_lds((gas_t*)ap, (las_t*)&As[w][0][0][0], 16, 0, 0);
        __builtin_amdgcn_global_load_lds((gas_t*)(ap + 8 * (size_t)MT),
                                         (las_t*)&As[w][0][8][0], 16, 0, 0);
        #pragma unroll
        for (int i = 0; i < 4; ++i)
            __builtin_amdgcn_global_load_lds((gas_t*)(bsrc + 2 * (size_t)i * ldb),
                                             (las_t*)&Bs[0][w * 8 + 2 * i][0], 16, 0, 0);
    }
    __syncthreads();

    for (int ti = 0; ti < nt; ++ti) {
        const int bf = ti & 1;
        // ---- stage tile ti+1 into buf^1 (6 insts/wave; lands before the sync) ----
        if (ti + 1 < nt) {
            const float* a2 = ap + (size_t)(ti + 1) * 16 * MT;
            const float* b2 = bsrc + (size_t)(ti + 1) * 16 * ldb;
            __builtin_amdgcn_global_load_lds((gas_t*)a2, (las_t*)&As[w][bf ^ 1][0][0], 16, 0, 0);
            __builtin_amdgcn_global_load_lds((gas_t*)(a2 + 8 * (size_t)MT),
                                             (las_t*)&As[w][bf ^ 1][8][0], 16, 0, 0);
            #pragma unroll
            for (int i = 0; i < 4; ++i)
                __builtin_amdgcn_global_load_lds((gas_t*)(b2 + 2 * (size_t)i * ldb),
                                                 (las_t*)&Bs[bf ^ 1][w * 8 + 2 * i][0], 16, 0, 0);
        }
        // ---- compute tile ti: 16 ascending k-steps, 64 fmaf chains per lane ----
        #pragma unroll
        for (int kk = 0; kk < 16; ++kk) {
            const float4 a0 = *(const float4*)&As[w][bf][kk][mq * 8];
            const float4 a1 = *(const float4*)&As[w][bf][kk][mq * 8 + 4];
            const float4 bv0 = *(const float4*)&Bs[bf][kk][cg * 8];
            const float4 bv1 = *(const float4*)&Bs[bf][kk][cg * 8 + 4];
            FMA8(a0.x, 0) FMA8(a0.y, 1) FMA8(a0.z, 2) FMA8(a0.w, 3)
            FMA8(a1.x, 4) FMA8(a1.y, 5) FMA8(a1.z, 6) FMA8(a1.w, 7)
        }
        // vmcnt(0)+lgkmcnt(0)+barrier: staging(ti+1) landed; all waves done reading buf
        __syncthreads();
    }

    const int mrow0 = m0 + mq * 8;
    #pragma unroll
    for (int r = 0; r < 8; ++r) {
        *(float4*)&part[((size_t)p * MT + mrow0 + r) * BATCH + cg * 8]     = acc[r][0];
        *(float4*)&part[((size_t)p * MT + mrow0 + r) * BATCH + cg * 8 + 4] = acc[r][1];
    }
}

// ---------------- LIF (ops mirror np exactly; verified R7-R16) ----------------
__device__ __forceinline__ float lif1e(float c, float& m)
{
    const float r = (m > 1.0f) ? 1.0f : 0.0f;
    const float mn = __fsub_rn(__fadd_rn(__fmul_rn(0.95f, m), c), r);
    m = mn;
    return (mn > 1.0f) ? 1.0f : 0.0f;
}

// fold P panels ascending (one __fadd_rn each) + bias + LIF; float4 per thread
__global__ __launch_bounds__(256)
void reduce_lif4(const float* __restrict__ part, int P, int Mdim,
                 const float* __restrict__ bias, float* __restrict__ mem,
                 float* __restrict__ spk)
{
#pragma clang fp reassociate(off)
    const int idx4 = blockIdx.x * 256 + threadIdx.x;
    const int idx = idx4 * 4;
    const size_t stride = (size_t)Mdim * BATCH;
    float4 tot = *(const float4*)&part[idx];
    for (int z = 1; z < P; ++z) {
        const float4 pv = *(const float4*)&part[(size_t)z * stride + idx];
        tot.x = __fadd_rn(tot.x, pv.x); tot.y = __fadd_rn(tot.y, pv.y);
        tot.z = __fadd_rn(tot.z, pv.z); tot.w = __fadd_rn(tot.w, pv.w);
    }
    const float bb = bias[idx >> 7];
    float4 mm = *(float4*)&mem[idx];
    float4 sp;
    sp.x = lif1e(__fadd_rn(tot.x, bb), mm.x);
    sp.y = lif1e(__fadd_rn(tot.y, bb), mm.y);
    sp.z = lif1e(__fadd_rn(tot.z, bb), mm.z);
    sp.w = lif1e(__fadd_rn(tot.w, bb), mm.w);
    *(float4*)&mem[idx] = mm;
    *(float4*)&spk[idx] = sp;
}

// out-layer fold: partials are [P][Mpad][BATCH] (Mpad=1024 zero-padded); C_DIM rows live
__global__ __launch_bounds__(256)
void reduce_lif_out4(const float* __restrict__ part, int P, int Mpad,
                     const float* __restrict__ bias, float* __restrict__ mem,
                     float* __restrict__ out)
{
#pragma clang fp reassociate(off)
    const int idx4 = blockIdx.x * 256 + threadIdx.x;
    if (idx4 >= (C_DIM * BATCH) / 4) return;
    const int idx = idx4 * 4;
    const int cc = idx >> 7, b = idx & 127;
    const size_t stride = (size_t)Mpad * BATCH;
    float4 tot = *(const float4*)&part[idx];
    for (int z = 1; z < P; ++z) {
        const float4 pv = *(const float4*)&part[(size_t)z * stride + idx];
        tot.x = __fadd_rn(tot.x, pv.x); tot.y = __fadd_rn(tot.y, pv.y);
        tot.z = __fadd_rn(tot.z, pv.z); tot.w = __fadd_rn(tot.w, pv.w);
    }
    const float bb = bias[cc];
    float4 mm = *(float4*)&mem[idx];
    float s;
    s = lif1e(__fadd_rn(tot.x, bb), mm.x); if (s > 0.f) out[(size_t)(b+0) * C_DIM + cc] += 1.0f;
    s = lif1e(__fadd_rn(tot.y, bb), mm.y); if (s > 0.f) out[(size_t)(b+1) * C_DIM + cc] += 1.0f;
    s = lif1e(__fadd_rn(tot.z, bb), mm.z); if (s > 0.f) out[(size_t)(b+2) * C_DIM + cc] += 1.0f;
    s = lif1e(__fadd_rn(tot.w, bb), mm.w); if (s > 0.f) out[(size_t)(b+3) * C_DIM + cc] += 1.0f;
    *(float4*)&mem[idx] = mm;
}

// ---------------- host ----------------
extern "C" void kernel_launch(void* const* d_in, const int* in_sizes, int n_in,
                              void* d_out, int out_size, void* d_ws, size_t ws_size,
                              hipStream_t stream)
{
    const float* x  = (const float*)d_in[0];
    const float* w1 = (const float*)d_in[1];
    const float* b1 = (const float*)d_in[2];
    const float* m1 = (const float*)d_in[3];
    const float* w2 = (const float*)d_in[4];
    const float* b2 = (const float*)d_in[5];
    const float* m2 = (const float*)d_in[6];
    const float* w3 = (const float*)d_in[7];
    const float* b3 = (const float*)d_in[8];
    const float* m3 = (const float*)d_in[9];
    const float* wo = (const float*)d_in[10];
    const float* bo = (const float*)d_in[11];
    float* out = (float*)d_out;
    float* ws  = (float*)d_ws;
    (void)in_sizes; (void)n_in; (void)ws_size;

    const size_t HB = (size_t)H_DIM * BATCH;        // 524288
    const size_t CB = (size_t)C_DIM * BATCH;        // 128000

    // ---- ws layout (floats) — total ≈ 252 MB (verified fits R12-R16) ----
    size_t off = 0;
    const size_t MEM1 = off; off += HB;
    const size_t MEM2 = off; off += HB;
    const size_t MEM3 = off; off += HB;
    const size_t MEMO = off; off += CB;
    const size_t stateFloats = off;                 // zeroed every call
    const size_t SPK1 = off; off += HB;
    const size_t SPK2 = off; off += HB;
    const size_t SPK3 = off; off += HB;
    const size_t PART = off; off += (size_t)P_K4096 * HB;       // 13 x [4096][128]
    const size_t EWT1 = off; off += (size_t)D_IN * H_DIM;       // [2048][4096]
    const size_t EWT2 = off; off += (size_t)H_DIM * H_DIM;      // [4096][4096]
    const size_t EWT3 = off; off += (size_t)H_DIM * H_DIM;
    const size_t WOT  = off; off += (size_t)H_DIM * WOT_LD;     // [4096][1024]
    const size_t XT   = off; off += (size_t)D_IN * N_ALL;       // [2048][3200]

    hipMemsetAsync(d_ws, 0, stateFloats * sizeof(float), stream);
    hipMemsetAsync(d_out, 0, (size_t)out_size * sizeof(float), stream);

    // ---- one-time transposes (premask fused; bit-exact products) ----
    {
        dim3 tb(32, 8);
        tmask_k<<<dim3(D_IN / 32, H_DIM / 32), tb, 0, stream>>>(ws + EWT1, w1, m1, H_DIM, D_IN, H_DIM);
        tmask_k<<<dim3(H_DIM / 32, H_DIM / 32), tb, 0, stream>>>(ws + EWT2, w2, m2, H_DIM, H_DIM, H_DIM);
        tmask_k<<<dim3(H_DIM / 32, H_DIM / 32), tb, 0, stream>>>(ws + EWT3, w3, m3, H_DIM, H_DIM, H_DIM);
        tmask_k<<<dim3(H_DIM / 32, WOT_LD / 32), tb, 0, stream>>>(ws + WOT, wo, nullptr, C_DIM, H_DIM, WOT_LD);
        tmask_k<<<dim3(D_IN / 32, N_ALL / 32), tb, 0, stream>>>(ws + XT, x, nullptr, N_ALL, D_IN, N_ALL);
    }

    const dim3 g1(P_K2048, H_DIM / 64);             // 7 x 64 = 448 2-wave blocks
    const dim3 g23(P_K4096, H_DIM / 64);            // 13 x 64 = 832 2-wave blocks
    const dim3 go(P_K4096, WOT_LD / 64);            // 13 x 16 = 208 2-wave blocks
    const int gLif4  = (int)(HB / 4 / 256);         // 512
    const int gLifO4 = (int)((CB / 4 + 255) / 256); // 125

    for (int t = 0; t < T_STEPS; ++t) {
        // layer 1: AT = EWT1 [2048][4096], B = XT [2048][3200] cols t*128..
        gemm_w<<<g1, 128, 0, stream>>>(ws + EWT1, ws + XT, ws + PART,
                                       H_DIM, D_IN, N_ALL, t * BATCH);
        reduce_lif4<<<gLif4, 256, 0, stream>>>(ws + PART, P_K2048, H_DIM, b1, ws + MEM1, ws + SPK1);

        // layer 2
        gemm_w<<<g23, 128, 0, stream>>>(ws + EWT2, ws + SPK1, ws + PART,
                                        H_DIM, H_DIM, BATCH, 0);
        reduce_lif4<<<gLif4, 256, 0, stream>>>(ws + PART, P_K4096, H_DIM, b2, ws + MEM2, ws + SPK2);

        // layer 3
        gemm_w<<<g23, 128, 0, stream>>>(ws + EWT3, ws + SPK2, ws + PART,
                                        H_DIM, H_DIM, BATCH, 0);
        reduce_lif4<<<gLif4, 256, 0, stream>>>(ws + PART, P_K4096, H_DIM, b3, ws + MEM3, ws + SPK3);

        // output layer (WOT zero-padded to 1024 rows)
        gemm_w<<<go, 128, 0, stream>>>(ws + WOT, ws + SPK3, ws + PART,
                                       WOT_LD, H_DIM, BATCH, 0);
        reduce_lif_out4<<<gLifO4, 256, 0, stream>>>(ws + PART, P_K4096, WOT_LD, bo, ws + MEMO, out);
    }
}

// Round 8
// 6179.713 us; speedup vs baseline: 1.0272x; 1.0272x over previous
//
#include <hip/hip_runtime.h>

#define T_STEPS 25
#define BATCH   128
#define D_IN    2048
#define H_DIM   4096
#define C_DIM   1000
#define N_ALL   3200
#define GEMM_Q  320   // OpenBLAS SGEMM_DEFAULT_Q, SKYLAKEX path (verified bit-exact R7-R16)
#define P_K2048 7     // panels: 320x5, 224, 224
#define P_K4096 13    // panels: 320x11, 288, 288
#define WOT_LD  1024  // wo^T padded out-M (1000 -> 1024, pad rows zero)

typedef __attribute__((address_space(1))) const void gas_t;
typedef __attribute__((address_space(3))) void las_t;

// OpenBLAS level3 K-panel schedule (verified bit-exact R7):
__device__ __forceinline__ int panel_len(int rem) {
    return (rem >= 2 * GEMM_Q) ? GEMM_Q
         : (rem > GEMM_Q ? ((rem / 2 + 15) & ~15) : rem);
}

// ---------------- transpose (+optional mask premultiply, zero-pad): dst[K][MT] ----------------
// Mask entries are exactly 0/1, so w*m is the identical fp32 product the reference forms.
__global__ __launch_bounds__(256)
void tmask_k(float* __restrict__ dst, const float* __restrict__ src,
             const float* __restrict__ msk, int M, int K, int MT)
{
    __shared__ float t[32][33];
    const int tx = threadIdx.x, ty = threadIdx.y;
    const int k0 = blockIdx.x * 32, m0 = blockIdx.y * 32;
    #pragma unroll
    for (int i = 0; i < 4; ++i) {
        const int m = m0 + ty + 8 * i;
        float v = 0.f;
        if (m < M) {
            const size_t gi = (size_t)m * K + k0 + tx;
            v = src[gi];
            if (msk) v *= msk[gi];
        }
        t[ty + 8 * i][tx] = v;
    }
    __syncthreads();
    const int mc = m0 + tx;
    if (mc < MT) {
        #pragma unroll
        for (int i = 0; i < 4; ++i)
            dst[(size_t)(k0 + ty + 8 * i) * MT + mc] = t[tx][ty + 8 * i];
    }
}

// ---------------- 2-wave shared-B GEMM: block = 64m x 128b, wave = 32m x 128b, lane = 8m x (4+4)b ----------------
// R7 structure with the bank-conflict fix. R7's bv0 = Bs[kk][cg*8] read float4
// granules at STRIDE 2 across lanes (granules 0,2,..30) -> 4.19M SQ_LDS_BANK_CONFLICT
// (per-16-lane phase no longer a linear 256B burst; 4-way serialize) which ate the
// whole RM8xC8 rebalance. Fix: lane owns cols [cg*4, cg*4+4) u [64+cg*4, 64+cg*4+4):
//   bv0 = granule cg (granules 0-15 unit-stride, 4-way broadcast - R0/R6's proven
//   conflict-free pattern), bv1 = granule 16+cg. Same B values, same ascending-k fmaf
//   chain per output element -> bit-exact; only lane->column ownership changes, and
//   both float4 stores stay coalesced (16 lanes = 256B contiguous per segment).
// Per CU-round: LDS 6.5 waves x 64 b128 ~= 4992 cyc (R6: 7488), VALU 3328, VMEM 39
// insts. Cadence per tile (R6-proven): [stage ti+1 -> buf^1 (6 insts/wave)]
// [compute ti] [__syncthreads]. part[p][m][b] = ascending-k fmaf chain per panel
// from zero; cross-panel folds ascend in the reduce kernels.
#define FMA8(AS, R)                                                   \
    acc[R][0].x = fmaf(AS, bv0.x, acc[R][0].x);                       \
    acc[R][0].y = fmaf(AS, bv0.y, acc[R][0].y);                       \
    acc[R][0].z = fmaf(AS, bv0.z, acc[R][0].z);                       \
    acc[R][0].w = fmaf(AS, bv0.w, acc[R][0].w);                       \
    acc[R][1].x = fmaf(AS, bv1.x, acc[R][1].x);                       \
    acc[R][1].y = fmaf(AS, bv1.y, acc[R][1].y);                       \
    acc[R][1].z = fmaf(AS, bv1.z, acc[R][1].z);                       \
    acc[R][1].w = fmaf(AS, bv1.w, acc[R][1].w);

__global__ __launch_bounds__(128)
void gemm_w(const float* __restrict__ AT, const float* __restrict__ B,
            float* __restrict__ part, int MT, int K, int ldb, int n0)
{
#pragma clang fp reassociate(off)
    __shared__ __align__(16) float Bs[2][16][128];    // 16 KB block-shared B tile (dbuf)
    __shared__ __align__(16) float As[2][2][16][32];  // 8 KB wave-private A tiles (dbuf)
    const int tid  = threadIdx.x;
    const int w    = tid >> 6;                        // wave 0..1
    const int lane = tid & 63;
    const int mq   = lane >> 4;                       // 0..3: 8 m-rows each
    const int cg   = lane & 15;                       // col-group
    const int m0   = blockIdx.y * 64 + w * 32;        // wave's 32-row m tile
    const int p    = blockIdx.x;

    int pstart = 0, rem = K, pl = panel_len(K);
    for (int i = 0; i < p; ++i) { pstart += pl; rem -= pl; pl = panel_len(rem); }
    const int nt = pl >> 4;                           // 320/288/224 all /16

    float4 acc[8][2];
    #pragma unroll
    for (int r = 0; r < 8; ++r) {
        acc[r][0] = make_float4(0.f, 0.f, 0.f, 0.f);
        acc[r][1] = make_float4(0.f, 0.f, 0.f, 0.f);
    }

    // A stage (per wave): [16k][32m] tile = 2KB = 2 insts; lane l -> (row l>>3, col (l&7)*4)
    const int akr = lane >> 3, amq = (lane & 7) * 4;
    const float* ap = AT + (size_t)(pstart + akr) * MT + m0 + amq;
    // B stage (2-wave cooperative): wave w rows w*8..w*8+7 via 4 insts;
    // inst i: lanes 0-31 -> row w*8+2i col (lane&31)*4, lanes 32-63 -> row w*8+2i+1
    const float* bsrc = B + (size_t)(pstart + w * 8 + (lane >> 5)) * ldb + n0 + (lane & 31) * 4;

    {   // prologue: stage tile 0
        __builtin_amdgcn_global_load_lds((gas_t*)ap, (las_t*)&As[w][0][0][0], 16, 0, 0);
        __builtin_amdgcn_global_load_lds((gas_t*)(ap + 8 * (size_t)MT),
                                         (las_t*)&As[w][0][8][0], 16, 0, 0);
        #pragma unroll
        for (int i = 0; i < 4; ++i)
            __builtin_amdgcn_global_load_lds((gas_t*)(bsrc + 2 * (size_t)i * ldb),
                                             (las_t*)&Bs[0][w * 8 + 2 * i][0], 16, 0, 0);
    }
    __syncthreads();

    for (int ti = 0; ti < nt; ++ti) {
        const int bf = ti & 1;
        // ---- stage tile ti+1 into buf^1 (6 insts/wave; lands before the sync) ----
        if (ti + 1 < nt) {
            const float* a2 = ap + (size_t)(ti + 1) * 16 * MT;
            const float* b2 = bsrc + (size_t)(ti + 1) * 16 * ldb;
            __builtin_amdgcn_global_load_lds((gas_t*)a2, (las_t*)&As[w][bf ^ 1][0][0], 16, 0, 0);
            __builtin_amdgcn_global_load_lds((gas_t*)(a2 + 8 * (size_t)MT),
                                             (las_t*)&As[w][bf ^ 1][8][0], 16, 0, 0);
            #pragma unroll
            for (int i = 0; i < 4; ++i)
                __builtin_amdgcn_global_load_lds((gas_t*)(b2 + 2 * (size_t)i * ldb),
                                                 (las_t*)&Bs[bf ^ 1][w * 8 + 2 * i][0], 16, 0, 0);
        }
        // ---- compute tile ti: 16 ascending k-steps, 64 fmaf chains per lane ----
        #pragma unroll
        for (int kk = 0; kk < 16; ++kk) {
            const float4 a0 = *(const float4*)&As[w][bf][kk][mq * 8];
            const float4 a1 = *(const float4*)&As[w][bf][kk][mq * 8 + 4];
            const float4 bv0 = *(const float4*)&Bs[bf][kk][cg * 4];        // granules 0-15: unit stride
            const float4 bv1 = *(const float4*)&Bs[bf][kk][64 + cg * 4];   // granules 16-31: unit stride
            FMA8(a0.x, 0) FMA8(a0.y, 1) FMA8(a0.z, 2) FMA8(a0.w, 3)
            FMA8(a1.x, 4) FMA8(a1.y, 5) FMA8(a1.z, 6) FMA8(a1.w, 7)
        }
        // vmcnt(0)+lgkmcnt(0)+barrier: staging(ti+1) landed; all waves done reading buf
        __syncthreads();
    }

    const int mrow0 = m0 + mq * 8;
    #pragma unroll
    for (int r = 0; r < 8; ++r) {
        *(float4*)&part[((size_t)p * MT + mrow0 + r) * BATCH + cg * 4]      = acc[r][0];
        *(float4*)&part[((size_t)p * MT + mrow0 + r) * BATCH + 64 + cg * 4] = acc[r][1];
    }
}

// ---------------- LIF (ops mirror np exactly; verified R7-R16) ----------------
__device__ __forceinline__ float lif1e(float c, float& m)
{
    const float r = (m > 1.0f) ? 1.0f : 0.0f;
    const float mn = __fsub_rn(__fadd_rn(__fmul_rn(0.95f, m), c), r);
    m = mn;
    return (mn > 1.0f) ? 1.0f : 0.0f;
}

// fold P panels ascending (one __fadd_rn each) + bias + LIF; float4 per thread
__global__ __launch_bounds__(256)
void reduce_lif4(const float* __restrict__ part, int P, int Mdim,
                 const float* __restrict__ bias, float* __restrict__ mem,
                 float* __restrict__ spk)
{
#pragma clang fp reassociate(off)
    const int idx4 = blockIdx.x * 256 + threadIdx.x;
    const int idx = idx4 * 4;
    const size_t stride = (size_t)Mdim * BATCH;
    float4 tot = *(const float4*)&part[idx];
    for (int z = 1; z < P; ++z) {
        const float4 pv = *(const float4*)&part[(size_t)z * stride + idx];
        tot.x = __fadd_rn(tot.x, pv.x); tot.y = __fadd_rn(tot.y, pv.y);
        tot.z = __fadd_rn(tot.z, pv.z); tot.w = __fadd_rn(tot.w, pv.w);
    }
    const float bb = bias[idx >> 7];
    float4 mm = *(float4*)&mem[idx];
    float4 sp;
    sp.x = lif1e(__fadd_rn(tot.x, bb), mm.x);
    sp.y = lif1e(__fadd_rn(tot.y, bb), mm.y);
    sp.z = lif1e(__fadd_rn(tot.z, bb), mm.z);
    sp.w = lif1e(__fadd_rn(tot.w, bb), mm.w);
    *(float4*)&mem[idx] = mm;
    *(float4*)&spk[idx] = sp;
}

// out-layer fold: partials are [P][Mpad][BATCH] (Mpad=1024 zero-padded); C_DIM rows live
__global__ __launch_bounds__(256)
void reduce_lif_out4(const float* __restrict__ part, int P, int Mpad,
                     const float* __restrict__ bias, float* __restrict__ mem,
                     float* __restrict__ out)
{
#pragma clang fp reassociate(off)
    const int idx4 = blockIdx.x * 256 + threadIdx.x;
    if (idx4 >= (C_DIM * BATCH) / 4) return;
    const int idx = idx4 * 4;
    const int cc = idx >> 7, b = idx & 127;
    const size_t stride = (size_t)Mpad * BATCH;
    float4 tot = *(const float4*)&part[idx];
    for (int z = 1; z < P; ++z) {
        const float4 pv = *(const float4*)&part[(size_t)z * stride + idx];
        tot.x = __fadd_rn(tot.x, pv.x); tot.y = __fadd_rn(tot.y, pv.y);
        tot.z = __fadd_rn(tot.z, pv.z); tot.w = __fadd_rn(tot.w, pv.w);
    }
    const float bb = bias[cc];
    float4 mm = *(float4*)&mem[idx];
    float s;
    s = lif1e(__fadd_rn(tot.x, bb), mm.x); if (s > 0.f) out[(size_t)(b+0) * C_DIM + cc] += 1.0f;
    s = lif1e(__fadd_rn(tot.y, bb), mm.y); if (s > 0.f) out[(size_t)(b+1) * C_DIM + cc] += 1.0f;
    s = lif1e(__fadd_rn(tot.z, bb), mm.z); if (s > 0.f) out[(size_t)(b+2) * C_DIM + cc] += 1.0f;
    s = lif1e(__fadd_rn(tot.w, bb), mm.w); if (s > 0.f) out[(size_t)(b+3) * C_DIM + cc] += 1.0f;
    *(float4*)&mem[idx] = mm;
}

// ---------------- host ----------------
extern "C" void kernel_launch(void* const* d_in, const int* in_sizes, int n_in,
                              void* d_out, int out_size, void* d_ws, size_t ws_size,
                              hipStream_t stream)
{
    const float* x  = (const float*)d_in[0];
    const float* w1 = (const float*)d_in[1];
    const float* b1 = (const float*)d_in[2];
    const float* m1 = (const float*)d_in[3];
    const float* w2 = (const float*)d_in[4];
    const float* b2 = (const float*)d_in[5];
    const float* m2 = (const float*)d_in[6];
    const float* w3 = (const float*)d_in[7];
    const float* b3 = (const float*)d_in[8];
    const float* m3 = (const float*)d_in[9];
    const float* wo = (const float*)d_in[10];
    const float* bo = (const float*)d_in[11];
    float* out = (float*)d_out;
    float* ws  = (float*)d_ws;
    (void)in_sizes; (void)n_in; (void)ws_size;

    const size_t HB = (size_t)H_DIM * BATCH;        // 524288
    const size_t CB = (size_t)C_DIM * BATCH;        // 128000

    // ---- ws layout (floats) — total ≈ 252 MB (verified fits R12-R16) ----
    size_t off = 0;
    const size_t MEM1 = off; off += HB;
    const size_t MEM2 = off; off += HB;
    const size_t MEM3 = off; off += HB;
    const size_t MEMO = off; off += CB;
    const size_t stateFloats = off;                 // zeroed every call
    const size_t SPK1 = off; off += HB;
    const size_t SPK2 = off; off += HB;
    const size_t SPK3 = off; off += HB;
    const size_t PART = off; off += (size_t)P_K4096 * HB;       // 13 x [4096][128]
    const size_t EWT1 = off; off += (size_t)D_IN * H_DIM;       // [2048][4096]
    const size_t EWT2 = off; off += (size_t)H_DIM * H_DIM;      // [4096][4096]
    const size_t EWT3 = off; off += (size_t)H_DIM * H_DIM;
    const size_t WOT  = off; off += (size_t)H_DIM * WOT_LD;     // [4096][1024]
    const size_t XT   = off; off += (size_t)D_IN * N_ALL;       // [2048][3200]

    hipMemsetAsync(d_ws, 0, stateFloats * sizeof(float), stream);
    hipMemsetAsync(d_out, 0, (size_t)out_size * sizeof(float), stream);

    // ---- one-time transposes (premask fused; bit-exact products) ----
    {
        dim3 tb(32, 8);
        tmask_k<<<dim3(D_IN / 32, H_DIM / 32), tb, 0, stream>>>(ws + EWT1, w1, m1, H_DIM, D_IN, H_DIM);
        tmask_k<<<dim3(H_DIM / 32, H_DIM / 32), tb, 0, stream>>>(ws + EWT2, w2, m2, H_DIM, H_DIM, H_DIM);
        tmask_k<<<dim3(H_DIM / 32, H_DIM / 32), tb, 0, stream>>>(ws + EWT3, w3, m3, H_DIM, H_DIM, H_DIM);
        tmask_k<<<dim3(H_DIM / 32, WOT_LD / 32), tb, 0, stream>>>(ws + WOT, wo, nullptr, C_DIM, H_DIM, WOT_LD);
        tmask_k<<<dim3(D_IN / 32, N_ALL / 32), tb, 0, stream>>>(ws + XT, x, nullptr, N_ALL, D_IN, N_ALL);
    }

    const dim3 g1(P_K2048, H_DIM / 64);             // 7 x 64 = 448 2-wave blocks
    const dim3 g23(P_K4096, H_DIM / 64);            // 13 x 64 = 832 2-wave blocks
    const dim3 go(P_K4096, WOT_LD / 64);            // 13 x 16 = 208 2-wave blocks
    const int gLif4  = (int)(HB / 4 / 256);         // 512
    const int gLifO4 = (int)((CB / 4 + 255) / 256); // 125

    for (int t = 0; t < T_STEPS; ++t) {
        // layer 1: AT = EWT1 [2048][4096], B = XT [2048][3200] cols t*128..
        gemm_w<<<g1, 128, 0, stream>>>(ws + EWT1, ws + XT, ws + PART,
                                       H_DIM, D_IN, N_ALL, t * BATCH);
        reduce_lif4<<<gLif4, 256, 0, stream>>>(ws + PART, P_K2048, H_DIM, b1, ws + MEM1, ws + SPK1);

        // layer 2
        gemm_w<<<g23, 128, 0, stream>>>(ws + EWT2, ws + SPK1, ws + PART,
                                        H_DIM, H_DIM, BATCH, 0);
        reduce_lif4<<<gLif4, 256, 0, stream>>>(ws + PART, P_K4096, H_DIM, b2, ws + MEM2, ws + SPK2);

        // layer 3
        gemm_w<<<g23, 128, 0, stream>>>(ws + EWT3, ws + SPK2, ws + PART,
                                        H_DIM, H_DIM, BATCH, 0);
        reduce_lif4<<<gLif4, 256, 0, stream>>>(ws + PART, P_K4096, H_DIM, b3, ws + MEM3, ws + SPK3);

        // output layer (WOT zero-padded to 1024 rows)
        gemm_w<<<go, 128, 0, stream>>>(ws + WOT, ws + SPK3, ws + PART,
                                       WOT_LD, H_DIM, BATCH, 0);
        reduce_lif_out4<<<gLifO4, 256, 0, stream>>>(ws + PART, P_K4096, WOT_LD, bo, ws + MEMO, out);
    }
}

// Round 9
// 5653.511 us; speedup vs baseline: 1.1228x; 1.0931x over previous
//
#include <hip/hip_runtime.h>

#define T_STEPS 25
#define BATCH   128
#define D_IN    2048
#define H_DIM   4096
#define C_DIM   1000
#define N_ALL   3200
#define GEMM_Q  320   // OpenBLAS SGEMM_DEFAULT_Q, SKYLAKEX path (verified bit-exact R7-R16)
#define P_K2048 7     // panels: 320x5, 224, 224
#define P_K4096 13    // panels: 320x11, 288, 288
#define WOT_LD  1024  // wo^T padded out-M (1000 -> 1024, pad rows zero)

typedef __attribute__((address_space(1))) const void gas_t;
typedef __attribute__((address_space(3))) void las_t;

// OpenBLAS level3 K-panel schedule (verified bit-exact R7):
__device__ __forceinline__ int panel_len(int rem) {
    return (rem >= 2 * GEMM_Q) ? GEMM_Q
         : (rem > GEMM_Q ? ((rem / 2 + 15) & ~15) : rem);
}

// ---------------- transpose (+optional mask premultiply, zero-pad): dst[K][MT] ----------------
// Mask entries are exactly 0/1, so w*m is the identical fp32 product the reference forms.
__global__ __launch_bounds__(256)
void tmask_k(float* __restrict__ dst, const float* __restrict__ src,
             const float* __restrict__ msk, int M, int K, int MT)
{
    __shared__ float t[32][33];
    const int tx = threadIdx.x, ty = threadIdx.y;
    const int k0 = blockIdx.x * 32, m0 = blockIdx.y * 32;
    #pragma unroll
    for (int i = 0; i < 4; ++i) {
        const int m = m0 + ty + 8 * i;
        float v = 0.f;
        if (m < M) {
            const size_t gi = (size_t)m * K + k0 + tx;
            v = src[gi];
            if (msk) v *= msk[gi];
        }
        t[ty + 8 * i][tx] = v;
    }
    __syncthreads();
    const int mc = m0 + tx;
    if (mc < MT) {
        #pragma unroll
        for (int i = 0; i < 4; ++i)
            dst[(size_t)(k0 + ty + 8 * i) * MT + mc] = t[tx][ty + 8 * i];
    }
}

// ---------------- 2-wave shared-B GEMM: block = 32m x 128b, wave = 16m x 128b, lane = 8m x 4b ----------------
// R6's verified inner loop (RM8C4: mg = lane>>5 m-half, lc = lane&31 col-quad;
// broadcast A reads + unit-stride B granules, 0 conflicts) with FINER BLOCKS.
// Evidence R6 vs R8 vs R0: more resident waves wins at equal barrier groups; the
// round (8800cyc) is ~2.6x the VALU wall (3328) -> latency exposure hidden only by
// wave TLP. R6's TLP was throttled by (a) load imbalance: 832 blocks/256 CU = 3.25,
// the 64 CUs holding 4 blocks set the pace (19% waste); (b) only 3.25 independent
// barrier groups/CU. This split: grid 13x128 = 1664 2-wave blocks = 6.5/CU -> tail
// 7%, 6.5 independent groups/CU (SIMD sees ~3.25 waves from ~3 different groups ->
// barrier stalls interleave). Waves/CU unchanged (13). LDS 20KB/block (7 resident).
// VMEM 10 insts/block-tile -> 65/CU-round, under the ~40cyc/inst service wall.
// All values pass through LDS bit-unmodified; ascending-k fmaf chain + OpenBLAS
// panel split untouched -> bit-exact. Cadence per tile (R6-proven): [stage ti+1 ->
// buf^1 (5 insts/wave)] [compute ti] [__syncthreads]. part[p][m][b] = ascending-k
// fmaf chain per panel from zero; cross-panel folds ascend in the reduce kernels.
#define FMAQ(AS, R)                                                   \
    acc[R].x = fmaf(AS, bv.x, acc[R].x);                              \
    acc[R].y = fmaf(AS, bv.y, acc[R].y);                              \
    acc[R].z = fmaf(AS, bv.z, acc[R].z);                              \
    acc[R].w = fmaf(AS, bv.w, acc[R].w);

__global__ __launch_bounds__(128)
void gemm_w(const float* __restrict__ AT, const float* __restrict__ B,
            float* __restrict__ part, int MT, int K, int ldb, int n0)
{
#pragma clang fp reassociate(off)
    __shared__ __align__(16) float Bs[2][16][128];    // 16 KB block-shared B tile (dbuf)
    __shared__ __align__(16) float As[2][2][16][16];  // 4 KB wave-private A tiles (dbuf)
    const int tid  = threadIdx.x;
    const int w    = tid >> 6;                        // wave 0..1
    const int lane = tid & 63;
    const int mg   = lane >> 5;                       // 0/1: m-half within wave tile
    const int lc   = lane & 31;                       // b-col quad
    const int m0   = blockIdx.y * 32 + w * 16;        // wave's 16-row m tile
    const int p    = blockIdx.x;

    int pstart = 0, rem = K, pl = panel_len(K);
    for (int i = 0; i < p; ++i) { pstart += pl; rem -= pl; pl = panel_len(rem); }
    const int nt = pl >> 4;                           // 320/288/224 all /16

    float4 acc[8];
    #pragma unroll
    for (int r = 0; r < 8; ++r) acc[r] = make_float4(0.f, 0.f, 0.f, 0.f);

    // A stage (per wave, R6 pattern): lane l -> (k-row l>>2, m-quad l&3); dest lane-linear
    const int akr = lane >> 2, amq = (lane & 3) * 4;
    const float* ap = AT + (size_t)(pstart + akr) * MT + m0 + amq;
    // B stage (2-wave cooperative): wave w covers rows w*8..w*8+7 via 4 insts;
    // inst i: lanes 0-31 -> row w*8+2i col (lane&31)*4, lanes 32-63 -> row w*8+2i+1
    const float* bsrc = B + (size_t)(pstart + w * 8 + (lane >> 5)) * ldb + n0 + (lane & 31) * 4;

    {   // prologue: stage tile 0 (A 1 inst/wave, B 4 insts/wave)
        __builtin_amdgcn_global_load_lds((gas_t*)ap, (las_t*)&As[w][0][0][0], 16, 0, 0);
        #pragma unroll
        for (int i = 0; i < 4; ++i)
            __builtin_amdgcn_global_load_lds((gas_t*)(bsrc + 2 * (size_t)i * ldb),
                                             (las_t*)&Bs[0][w * 8 + 2 * i][0], 16, 0, 0);
    }
    __syncthreads();

    for (int ti = 0; ti < nt; ++ti) {
        const int bf = ti & 1;
        // ---- stage tile ti+1 into buf^1 (5 insts/wave; lands before the sync) ----
        if (ti + 1 < nt) {
            const float* a2 = ap + (size_t)(ti + 1) * 16 * MT;
            const float* b2 = bsrc + (size_t)(ti + 1) * 16 * ldb;
            __builtin_amdgcn_global_load_lds((gas_t*)a2, (las_t*)&As[w][bf ^ 1][0][0], 16, 0, 0);
            #pragma unroll
            for (int i = 0; i < 4; ++i)
                __builtin_amdgcn_global_load_lds((gas_t*)(b2 + 2 * (size_t)i * ldb),
                                                 (las_t*)&Bs[bf ^ 1][w * 8 + 2 * i][0], 16, 0, 0);
        }
        // ---- compute tile ti: 16 ascending k-steps, 32 fmaf chains per lane ----
        #pragma unroll
        for (int kk = 0; kk < 16; ++kk) {
            const float4 a0 = *(const float4*)&As[w][bf][kk][mg * 8];
            const float4 a1 = *(const float4*)&As[w][bf][kk][mg * 8 + 4];
            const float4 bv = *(const float4*)&Bs[bf][kk][lc * 4];
            FMAQ(a0.x, 0) FMAQ(a0.y, 1) FMAQ(a0.z, 2) FMAQ(a0.w, 3)
            FMAQ(a1.x, 4) FMAQ(a1.y, 5) FMAQ(a1.z, 6) FMAQ(a1.w, 7)
        }
        // vmcnt(0)+lgkmcnt(0)+barrier: staging(ti+1) landed; all waves done reading buf
        __syncthreads();
    }

    const int mrow0 = m0 + mg * 8;
    #pragma unroll
    for (int r = 0; r < 8; ++r)
        *(float4*)&part[((size_t)p * MT + mrow0 + r) * BATCH + lc * 4] = acc[r];
}

// ---------------- LIF (ops mirror np exactly; verified R7-R16) ----------------
__device__ __forceinline__ float lif1e(float c, float& m)
{
    const float r = (m > 1.0f) ? 1.0f : 0.0f;
    const float mn = __fsub_rn(__fadd_rn(__fmul_rn(0.95f, m), c), r);
    m = mn;
    return (mn > 1.0f) ? 1.0f : 0.0f;
}

// fold P panels ascending (one __fadd_rn each) + bias + LIF; float4 per thread
__global__ __launch_bounds__(256)
void reduce_lif4(const float* __restrict__ part, int P, int Mdim,
                 const float* __restrict__ bias, float* __restrict__ mem,
                 float* __restrict__ spk)
{
#pragma clang fp reassociate(off)
    const int idx4 = blockIdx.x * 256 + threadIdx.x;
    const int idx = idx4 * 4;
    const size_t stride = (size_t)Mdim * BATCH;
    float4 tot = *(const float4*)&part[idx];
    for (int z = 1; z < P; ++z) {
        const float4 pv = *(const float4*)&part[(size_t)z * stride + idx];
        tot.x = __fadd_rn(tot.x, pv.x); tot.y = __fadd_rn(tot.y, pv.y);
        tot.z = __fadd_rn(tot.z, pv.z); tot.w = __fadd_rn(tot.w, pv.w);
    }
    const float bb = bias[idx >> 7];
    float4 mm = *(float4*)&mem[idx];
    float4 sp;
    sp.x = lif1e(__fadd_rn(tot.x, bb), mm.x);
    sp.y = lif1e(__fadd_rn(tot.y, bb), mm.y);
    sp.z = lif1e(__fadd_rn(tot.z, bb), mm.z);
    sp.w = lif1e(__fadd_rn(tot.w, bb), mm.w);
    *(float4*)&mem[idx] = mm;
    *(float4*)&spk[idx] = sp;
}

// out-layer fold: partials are [P][Mpad][BATCH] (Mpad=1024 zero-padded); C_DIM rows live
__global__ __launch_bounds__(256)
void reduce_lif_out4(const float* __restrict__ part, int P, int Mpad,
                     const float* __restrict__ bias, float* __restrict__ mem,
                     float* __restrict__ out)
{
#pragma clang fp reassociate(off)
    const int idx4 = blockIdx.x * 256 + threadIdx.x;
    if (idx4 >= (C_DIM * BATCH) / 4) return;
    const int idx = idx4 * 4;
    const int cc = idx >> 7, b = idx & 127;
    const size_t stride = (size_t)Mpad * BATCH;
    float4 tot = *(const float4*)&part[idx];
    for (int z = 1; z < P; ++z) {
        const float4 pv = *(const float4*)&part[(size_t)z * stride + idx];
        tot.x = __fadd_rn(tot.x, pv.x); tot.y = __fadd_rn(tot.y, pv.y);
        tot.z = __fadd_rn(tot.z, pv.z); tot.w = __fadd_rn(tot.w, pv.w);
    }
    const float bb = bias[cc];
    float4 mm = *(float4*)&mem[idx];
    float s;
    s = lif1e(__fadd_rn(tot.x, bb), mm.x); if (s > 0.f) out[(size_t)(b+0) * C_DIM + cc] += 1.0f;
    s = lif1e(__fadd_rn(tot.y, bb), mm.y); if (s > 0.f) out[(size_t)(b+1) * C_DIM + cc] += 1.0f;
    s = lif1e(__fadd_rn(tot.z, bb), mm.z); if (s > 0.f) out[(size_t)(b+2) * C_DIM + cc] += 1.0f;
    s = lif1e(__fadd_rn(tot.w, bb), mm.w); if (s > 0.f) out[(size_t)(b+3) * C_DIM + cc] += 1.0f;
    *(float4*)&mem[idx] = mm;
}

// ---------------- host ----------------
extern "C" void kernel_launch(void* const* d_in, const int* in_sizes, int n_in,
                              void* d_out, int out_size, void* d_ws, size_t ws_size,
                              hipStream_t stream)
{
    const float* x  = (const float*)d_in[0];
    const float* w1 = (const float*)d_in[1];
    const float* b1 = (const float*)d_in[2];
    const float* m1 = (const float*)d_in[3];
    const float* w2 = (const float*)d_in[4];
    const float* b2 = (const float*)d_in[5];
    const float* m2 = (const float*)d_in[6];
    const float* w3 = (const float*)d_in[7];
    const float* b3 = (const float*)d_in[8];
    const float* m3 = (const float*)d_in[9];
    const float* wo = (const float*)d_in[10];
    const float* bo = (const float*)d_in[11];
    float* out = (float*)d_out;
    float* ws  = (float*)d_ws;
    (void)in_sizes; (void)n_in; (void)ws_size;

    const size_t HB = (size_t)H_DIM * BATCH;        // 524288
    const size_t CB = (size_t)C_DIM * BATCH;        // 128000

    // ---- ws layout (floats) — total ≈ 252 MB (verified fits R12-R16) ----
    size_t off = 0;
    const size_t MEM1 = off; off += HB;
    const size_t MEM2 = off; off += HB;
    const size_t MEM3 = off; off += HB;
    const size_t MEMO = off; off += CB;
    const size_t stateFloats = off;                 // zeroed every call
    const size_t SPK1 = off; off += HB;
    const size_t SPK2 = off; off += HB;
    const size_t SPK3 = off; off += HB;
    const size_t PART = off; off += (size_t)P_K4096 * HB;       // 13 x [4096][128]
    const size_t EWT1 = off; off += (size_t)D_IN * H_DIM;       // [2048][4096]
    const size_t EWT2 = off; off += (size_t)H_DIM * H_DIM;      // [4096][4096]
    const size_t EWT3 = off; off += (size_t)H_DIM * H_DIM;
    const size_t WOT  = off; off += (size_t)H_DIM * WOT_LD;     // [4096][1024]
    const size_t XT   = off; off += (size_t)D_IN * N_ALL;       // [2048][3200]

    hipMemsetAsync(d_ws, 0, stateFloats * sizeof(float), stream);
    hipMemsetAsync(d_out, 0, (size_t)out_size * sizeof(float), stream);

    // ---- one-time transposes (premask fused; bit-exact products) ----
    {
        dim3 tb(32, 8);
        tmask_k<<<dim3(D_IN / 32, H_DIM / 32), tb, 0, stream>>>(ws + EWT1, w1, m1, H_DIM, D_IN, H_DIM);
        tmask_k<<<dim3(H_DIM / 32, H_DIM / 32), tb, 0, stream>>>(ws + EWT2, w2, m2, H_DIM, H_DIM, H_DIM);
        tmask_k<<<dim3(H_DIM / 32, H_DIM / 32), tb, 0, stream>>>(ws + EWT3, w3, m3, H_DIM, H_DIM, H_DIM);
        tmask_k<<<dim3(H_DIM / 32, WOT_LD / 32), tb, 0, stream>>>(ws + WOT, wo, nullptr, C_DIM, H_DIM, WOT_LD);
        tmask_k<<<dim3(D_IN / 32, N_ALL / 32), tb, 0, stream>>>(ws + XT, x, nullptr, N_ALL, D_IN, N_ALL);
    }

    const dim3 g1(P_K2048, H_DIM / 32);             // 7 x 128 = 896 2-wave blocks
    const dim3 g23(P_K4096, H_DIM / 32);            // 13 x 128 = 1664 2-wave blocks (6.5/CU)
    const dim3 go(P_K4096, WOT_LD / 32);            // 13 x 32 = 416 2-wave blocks
    const int gLif4  = (int)(HB / 4 / 256);         // 512
    const int gLifO4 = (int)((CB / 4 + 255) / 256); // 125

    for (int t = 0; t < T_STEPS; ++t) {
        // layer 1: AT = EWT1 [2048][4096], B = XT [2048][3200] cols t*128..
        gemm_w<<<g1, 128, 0, stream>>>(ws + EWT1, ws + XT, ws + PART,
                                       H_DIM, D_IN, N_ALL, t * BATCH);
        reduce_lif4<<<gLif4, 256, 0, stream>>>(ws + PART, P_K2048, H_DIM, b1, ws + MEM1, ws + SPK1);

        // layer 2
        gemm_w<<<g23, 128, 0, stream>>>(ws + EWT2, ws + SPK1, ws + PART,
                                        H_DIM, H_DIM, BATCH, 0);
        reduce_lif4<<<gLif4, 256, 0, stream>>>(ws + PART, P_K4096, H_DIM, b2, ws + MEM2, ws + SPK2);

        // layer 3
        gemm_w<<<g23, 128, 0, stream>>>(ws + EWT3, ws + SPK2, ws + PART,
                                        H_DIM, H_DIM, BATCH, 0);
        reduce_lif4<<<gLif4, 256, 0, stream>>>(ws + PART, P_K4096, H_DIM, b3, ws + MEM3, ws + SPK3);

        // output layer (WOT zero-padded to 1024 rows)
        gemm_w<<<go, 128, 0, stream>>>(ws + WOT, ws + SPK3, ws + PART,
                                       WOT_LD, H_DIM, BATCH, 0);
        reduce_lif_out4<<<gLifO4, 256, 0, stream>>>(ws + PART, P_K4096, WOT_LD, bo, ws + MEMO, out);
    }
}

// Round 10
// 5163.749 us; speedup vs baseline: 1.2293x; 1.0948x over previous
//
#include <hip/hip_runtime.h>

#define T_STEPS 25
#define BATCH   128
#define D_IN    2048
#define H_DIM   4096
#define C_DIM   1000
#define N_ALL   3200
#define GEMM_Q  320   // OpenBLAS SGEMM_DEFAULT_Q, SKYLAKEX path (verified bit-exact R7-R16)
#define P_K2048 7     // panels: 320x5, 224, 224
#define P_K4096 13    // panels: 320x11, 288, 288
#define WOT_LD  1024  // wo^T padded out-M (1000 -> 1024, pad rows zero)

typedef __attribute__((address_space(1))) const void gas_t;
typedef __attribute__((address_space(3))) void las_t;

// OpenBLAS level3 K-panel schedule (verified bit-exact R7):
__device__ __forceinline__ int panel_len(int rem) {
    return (rem >= 2 * GEMM_Q) ? GEMM_Q
         : (rem > GEMM_Q ? ((rem / 2 + 15) & ~15) : rem);
}

// ---------------- transpose (+optional mask premultiply, zero-pad): dst[K][MT] ----------------
// Mask entries are exactly 0/1, so w*m is the identical fp32 product the reference forms.
__global__ __launch_bounds__(256)
void tmask_k(float* __restrict__ dst, const float* __restrict__ src,
             const float* __restrict__ msk, int M, int K, int MT)
{
    __shared__ float t[32][33];
    const int tx = threadIdx.x, ty = threadIdx.y;
    const int k0 = blockIdx.x * 32, m0 = blockIdx.y * 32;
    #pragma unroll
    for (int i = 0; i < 4; ++i) {
        const int m = m0 + ty + 8 * i;
        float v = 0.f;
        if (m < M) {
            const size_t gi = (size_t)m * K + k0 + tx;
            v = src[gi];
            if (msk) v *= msk[gi];
        }
        t[ty + 8 * i][tx] = v;
    }
    __syncthreads();
    const int mc = m0 + tx;
    if (mc < MT) {
        #pragma unroll
        for (int i = 0; i < 4; ++i)
            dst[(size_t)(k0 + ty + 8 * i) * MT + mc] = t[tx][ty + 8 * i];
    }
}

// ---------------- 4-wave shared-B GEMM: block = 64m x 128b, wave = 16m, lane = 8m x 4b ----------------
// R6 config (verified best: 73.4us, 0 conflicts) + SOFTWARE-PIPELINED inner loop.
// R6 diagnosis: VGPR=52 (= acc 32 + temps) proves the compiler allocated ZERO LDS
// read-ahead; each kk ran [3 ds_reads -> ~120cyc lgkm wait -> 64cyc fmaf]; round =
// LDS 4160 + VALU 3328 + 1400 nearly SERIAL (measured 8944cyc, VALUBusy 42%).
// Fix: named-register prefetch of kk+1's (a0,a1,bv) issued BEFORE kk's 32 fmaf;
// compile-time rotation (full unroll -> no moves). Same loads, same values, same
// ascending-k fmaf order per accumulator -> bit-exact vs OpenBLAS reference.
// Cadence per tile (R6-proven): [stage ti+1 -> buf^1 (3 insts/wave)] [compute ti]
// [__syncthreads: vmcnt(0)+lgkmcnt(0) drains staging issued ~2000cyc earlier].
// part[p][m][b] = ascending-k fmaf chain per panel from zero; cross-panel folds
// ascend in the reduce kernels.
#define FMAQ(AS, R)                                                   \
    acc[R].x = fmaf(AS, bv.x, acc[R].x);                              \
    acc[R].y = fmaf(AS, bv.y, acc[R].y);                              \
    acc[R].z = fmaf(AS, bv.z, acc[R].z);                              \
    acc[R].w = fmaf(AS, bv.w, acc[R].w);

__global__ __launch_bounds__(256)
void gemm_w(const float* __restrict__ AT, const float* __restrict__ B,
            float* __restrict__ part, int MT, int K, int ldb, int n0)
{
#pragma clang fp reassociate(off)
    __shared__ __align__(16) float Bs[2][16][128];    // 16 KB block-shared B tile (dbuf)
    __shared__ __align__(16) float As[4][2][16][16];  // 8 KB wave-private A tiles (dbuf)
    const int tid  = threadIdx.x;
    const int w    = tid >> 6;                        // wave 0..3
    const int lane = tid & 63;
    const int mg   = lane >> 5;                       // 0/1: m-half within wave tile
    const int lc   = lane & 31;                       // b-col quad
    const int m0   = blockIdx.y * 64 + w * 16;        // wave's 16-row m tile
    const int p    = blockIdx.x;

    int pstart = 0, rem = K, pl = panel_len(K);
    for (int i = 0; i < p; ++i) { pstart += pl; rem -= pl; pl = panel_len(rem); }
    const int nt = pl >> 4;                           // 320/288/224 all /16

    float4 acc[8];
    #pragma unroll
    for (int r = 0; r < 8; ++r) acc[r] = make_float4(0.f, 0.f, 0.f, 0.f);

    // A stage (per wave, as R6): lane l -> (k-row l>>2, m-quad l&3); dest lane-linear
    const int akr = lane >> 2, amq = (lane & 3) * 4;
    const float* ap = AT + (size_t)(pstart + akr) * MT + m0 + amq;
    // B stage (block-cooperative): wave w covers rows w*4..w*4+3 via 2 insts;
    // inst i: lanes 0-31 -> row w*4+2i col lc*4, lanes 32-63 -> row w*4+2i+1
    const float* bsrc = B + (size_t)(pstart + w * 4 + (lane >> 5)) * ldb + n0 + lc * 4;

    {   // prologue: stage tile 0
        __builtin_amdgcn_global_load_lds((gas_t*)ap, (las_t*)&As[w][0][0][0], 16, 0, 0);
        __builtin_amdgcn_global_load_lds((gas_t*)bsrc,
                                         (las_t*)&Bs[0][w * 4][0], 16, 0, 0);
        __builtin_amdgcn_global_load_lds((gas_t*)(bsrc + 2 * (size_t)ldb),
                                         (las_t*)&Bs[0][w * 4 + 2][0], 16, 0, 0);
    }
    __syncthreads();

    for (int ti = 0; ti < nt; ++ti) {
        const int bf = ti & 1;
        // ---- stage tile ti+1 into buf^1 (3 insts/wave; lands before the sync) ----
        if (ti + 1 < nt) {
            const float* a2 = ap + (size_t)(ti + 1) * 16 * MT;
            const float* b2 = bsrc + (size_t)(ti + 1) * 16 * ldb;
            __builtin_amdgcn_global_load_lds((gas_t*)a2, (las_t*)&As[w][bf ^ 1][0][0], 16, 0, 0);
            __builtin_amdgcn_global_load_lds((gas_t*)b2,
                                             (las_t*)&Bs[bf ^ 1][w * 4][0], 16, 0, 0);
            __builtin_amdgcn_global_load_lds((gas_t*)(b2 + 2 * (size_t)ldb),
                                             (las_t*)&Bs[bf ^ 1][w * 4 + 2][0], 16, 0, 0);
        }
        // ---- compute tile ti: software-pipelined 16 ascending k-steps ----
        // kk+1's operands are loaded into fresh registers BEFORE kk's fmaf burst;
        // full unroll makes the rotation free. Values/order identical to R6.
        {
            float4 a0 = *(const float4*)&As[w][bf][0][mg * 8];
            float4 a1 = *(const float4*)&As[w][bf][0][mg * 8 + 4];
            float4 bv = *(const float4*)&Bs[bf][0][lc * 4];
            #pragma unroll
            for (int kk = 0; kk < 16; ++kk) {
                float4 na0, na1, nbv;
                if (kk < 15) {
                    na0 = *(const float4*)&As[w][bf][kk + 1][mg * 8];
                    na1 = *(const float4*)&As[w][bf][kk + 1][mg * 8 + 4];
                    nbv = *(const float4*)&Bs[bf][kk + 1][lc * 4];
                }
                FMAQ(a0.x, 0) FMAQ(a0.y, 1) FMAQ(a0.z, 2) FMAQ(a0.w, 3)
                FMAQ(a1.x, 4) FMAQ(a1.y, 5) FMAQ(a1.z, 6) FMAQ(a1.w, 7)
                if (kk < 15) { a0 = na0; a1 = na1; bv = nbv; }
            }
        }
        // vmcnt(0)+lgkmcnt(0)+barrier: staging(ti+1) landed; all waves done reading buf
        __syncthreads();
    }

    const int mrow0 = m0 + mg * 8;
    #pragma unroll
    for (int r = 0; r < 8; ++r)
        *(float4*)&part[((size_t)p * MT + mrow0 + r) * BATCH + lc * 4] = acc[r];
}

// ---------------- LIF (ops mirror np exactly; verified R7-R16) ----------------
__device__ __forceinline__ float lif1e(float c, float& m)
{
    const float r = (m > 1.0f) ? 1.0f : 0.0f;
    const float mn = __fsub_rn(__fadd_rn(__fmul_rn(0.95f, m), c), r);
    m = mn;
    return (mn > 1.0f) ? 1.0f : 0.0f;
}

// fold P panels ascending (one __fadd_rn each) + bias + LIF; float4 per thread
__global__ __launch_bounds__(256)
void reduce_lif4(const float* __restrict__ part, int P, int Mdim,
                 const float* __restrict__ bias, float* __restrict__ mem,
                 float* __restrict__ spk)
{
#pragma clang fp reassociate(off)
    const int idx4 = blockIdx.x * 256 + threadIdx.x;
    const int idx = idx4 * 4;
    const size_t stride = (size_t)Mdim * BATCH;
    float4 tot = *(const float4*)&part[idx];
    for (int z = 1; z < P; ++z) {
        const float4 pv = *(const float4*)&part[(size_t)z * stride + idx];
        tot.x = __fadd_rn(tot.x, pv.x); tot.y = __fadd_rn(tot.y, pv.y);
        tot.z = __fadd_rn(tot.z, pv.z); tot.w = __fadd_rn(tot.w, pv.w);
    }
    const float bb = bias[idx >> 7];
    float4 mm = *(float4*)&mem[idx];
    float4 sp;
    sp.x = lif1e(__fadd_rn(tot.x, bb), mm.x);
    sp.y = lif1e(__fadd_rn(tot.y, bb), mm.y);
    sp.z = lif1e(__fadd_rn(tot.z, bb), mm.z);
    sp.w = lif1e(__fadd_rn(tot.w, bb), mm.w);
    *(float4*)&mem[idx] = mm;
    *(float4*)&spk[idx] = sp;
}

// out-layer fold: partials are [P][Mpad][BATCH] (Mpad=1024 zero-padded); C_DIM rows live
__global__ __launch_bounds__(256)
void reduce_lif_out4(const float* __restrict__ part, int P, int Mpad,
                     const float* __restrict__ bias, float* __restrict__ mem,
                     float* __restrict__ out)
{
#pragma clang fp reassociate(off)
    const int idx4 = blockIdx.x * 256 + threadIdx.x;
    if (idx4 >= (C_DIM * BATCH) / 4) return;
    const int idx = idx4 * 4;
    const int cc = idx >> 7, b = idx & 127;
    const size_t stride = (size_t)Mpad * BATCH;
    float4 tot = *(const float4*)&part[idx];
    for (int z = 1; z < P; ++z) {
        const float4 pv = *(const float4*)&part[(size_t)z * stride + idx];
        tot.x = __fadd_rn(tot.x, pv.x); tot.y = __fadd_rn(tot.y, pv.y);
        tot.z = __fadd_rn(tot.z, pv.z); tot.w = __fadd_rn(tot.w, pv.w);
    }
    const float bb = bias[cc];
    float4 mm = *(float4*)&mem[idx];
    float s;
    s = lif1e(__fadd_rn(tot.x, bb), mm.x); if (s > 0.f) out[(size_t)(b+0) * C_DIM + cc] += 1.0f;
    s = lif1e(__fadd_rn(tot.y, bb), mm.y); if (s > 0.f) out[(size_t)(b+1) * C_DIM + cc] += 1.0f;
    s = lif1e(__fadd_rn(tot.z, bb), mm.z); if (s > 0.f) out[(size_t)(b+2) * C_DIM + cc] += 1.0f;
    s = lif1e(__fadd_rn(tot.w, bb), mm.w); if (s > 0.f) out[(size_t)(b+3) * C_DIM + cc] += 1.0f;
    *(float4*)&mem[idx] = mm;
}

// ---------------- host ----------------
extern "C" void kernel_launch(void* const* d_in, const int* in_sizes, int n_in,
                              void* d_out, int out_size, void* d_ws, size_t ws_size,
                              hipStream_t stream)
{
    const float* x  = (const float*)d_in[0];
    const float* w1 = (const float*)d_in[1];
    const float* b1 = (const float*)d_in[2];
    const float* m1 = (const float*)d_in[3];
    const float* w2 = (const float*)d_in[4];
    const float* b2 = (const float*)d_in[5];
    const float* m2 = (const float*)d_in[6];
    const float* w3 = (const float*)d_in[7];
    const float* b3 = (const float*)d_in[8];
    const float* m3 = (const float*)d_in[9];
    const float* wo = (const float*)d_in[10];
    const float* bo = (const float*)d_in[11];
    float* out = (float*)d_out;
    float* ws  = (float*)d_ws;
    (void)in_sizes; (void)n_in; (void)ws_size;

    const size_t HB = (size_t)H_DIM * BATCH;        // 524288
    const size_t CB = (size_t)C_DIM * BATCH;        // 128000

    // ---- ws layout (floats) — total ≈ 252 MB (verified fits R12-R16) ----
    size_t off = 0;
    const size_t MEM1 = off; off += HB;
    const size_t MEM2 = off; off += HB;
    const size_t MEM3 = off; off += HB;
    const size_t MEMO = off; off += CB;
    const size_t stateFloats = off;                 // zeroed every call
    const size_t SPK1 = off; off += HB;
    const size_t SPK2 = off; off += HB;
    const size_t SPK3 = off; off += HB;
    const size_t PART = off; off += (size_t)P_K4096 * HB;       // 13 x [4096][128]
    const size_t EWT1 = off; off += (size_t)D_IN * H_DIM;       // [2048][4096]
    const size_t EWT2 = off; off += (size_t)H_DIM * H_DIM;      // [4096][4096]
    const size_t EWT3 = off; off += (size_t)H_DIM * H_DIM;
    const size_t WOT  = off; off += (size_t)H_DIM * WOT_LD;     // [4096][1024]
    const size_t XT   = off; off += (size_t)D_IN * N_ALL;       // [2048][3200]

    hipMemsetAsync(d_ws, 0, stateFloats * sizeof(float), stream);
    hipMemsetAsync(d_out, 0, (size_t)out_size * sizeof(float), stream);

    // ---- one-time transposes (premask fused; bit-exact products) ----
    {
        dim3 tb(32, 8);
        tmask_k<<<dim3(D_IN / 32, H_DIM / 32), tb, 0, stream>>>(ws + EWT1, w1, m1, H_DIM, D_IN, H_DIM);
        tmask_k<<<dim3(H_DIM / 32, H_DIM / 32), tb, 0, stream>>>(ws + EWT2, w2, m2, H_DIM, H_DIM, H_DIM);
        tmask_k<<<dim3(H_DIM / 32, H_DIM / 32), tb, 0, stream>>>(ws + EWT3, w3, m3, H_DIM, H_DIM, H_DIM);
        tmask_k<<<dim3(H_DIM / 32, WOT_LD / 32), tb, 0, stream>>>(ws + WOT, wo, nullptr, C_DIM, H_DIM, WOT_LD);
        tmask_k<<<dim3(D_IN / 32, N_ALL / 32), tb, 0, stream>>>(ws + XT, x, nullptr, N_ALL, D_IN, N_ALL);
    }

    const dim3 g1(P_K2048, H_DIM / 64);             // 7 x 64 = 448 4-wave blocks
    const dim3 g23(P_K4096, H_DIM / 64);            // 13 x 64 = 832 4-wave blocks
    const dim3 go(P_K4096, WOT_LD / 64);            // 13 x 16 = 208 4-wave blocks
    const int gLif4  = (int)(HB / 4 / 256);         // 512
    const int gLifO4 = (int)((CB / 4 + 255) / 256); // 125

    for (int t = 0; t < T_STEPS; ++t) {
        // layer 1: AT = EWT1 [2048][4096], B = XT [2048][3200] cols t*128..
        gemm_w<<<g1, 256, 0, stream>>>(ws + EWT1, ws + XT, ws + PART,
                                       H_DIM, D_IN, N_ALL, t * BATCH);
        reduce_lif4<<<gLif4, 256, 0, stream>>>(ws + PART, P_K2048, H_DIM, b1, ws + MEM1, ws + SPK1);

        // layer 2
        gemm_w<<<g23, 256, 0, stream>>>(ws + EWT2, ws + SPK1, ws + PART,
                                        H_DIM, H_DIM, BATCH, 0);
        reduce_lif4<<<gLif4, 256, 0, stream>>>(ws + PART, P_K4096, H_DIM, b2, ws + MEM2, ws + SPK2);

        // layer 3
        gemm_w<<<g23, 256, 0, stream>>>(ws + EWT3, ws + SPK2, ws + PART,
                                        H_DIM, H_DIM, BATCH, 0);
        reduce_lif4<<<gLif4, 256, 0, stream>>>(ws + PART, P_K4096, H_DIM, b3, ws + MEM3, ws + SPK3);

        // output layer (WOT zero-padded to 1024 rows)
        gemm_w<<<go, 256, 0, stream>>>(ws + WOT, ws + SPK3, ws + PART,
                                       WOT_LD, H_DIM, BATCH, 0);
        reduce_lif_out4<<<gLifO4, 256, 0, stream>>>(ws + PART, P_K4096, WOT_LD, bo, ws + MEMO, out);
    }
}